// Round 5
// baseline (214.283 us; speedup 1.0000x reference)
//
#include <hip/hip_runtime.h>
#include <math.h>

// PHM adapter: down (768->192, n=4 rank-1 kron) -> gelu_new -> up (192->768).
// Round 5: rounds 2/4 are latency-bound (~80us vs ~25us HBM floor, all pipes
// <30% busy): global-load round trip exposed once per tile in the serial
// load->compute->store structure. Fixes:
//  (1) amdgpu_waves_per_eu(4,4): LDS caps us at 4 blocks/CU anyway; pin the
//      allocator to a 128-VGPR budget so it stops choosing 64 regs + scratch
//      spill (round 4: WRITE +9216KB, VALUBusy 16%).
//  (2) register-prefetch pipeline: issue next tile's 6 float4 loads before
//      compute of the current tile; latency hides under compute+store.
// Keeps: coalesced LDS-staged I/O (round 2), DPP reduce + xor-swizzle gather
// (round 3), 2-token weight-read amortization (round 4).

#define SQ2PI 0.79788456080286535588f
#define T_TILE 8   // tokens per tile; 24 KB; 4 waves x 2 tokens

template<int CTRL>
__device__ __forceinline__ float ror_add(float v) {
    // v + rotate_within_16(v, CTRL)  (DPP row_ror — VALU pipe, no DS traffic)
    int s = __builtin_amdgcn_update_dpp(0, __float_as_int(v), CTRL, 0xF, 0xF, true);
    return v + __int_as_float(s);
}
__device__ __forceinline__ float reduce16(float v) {
    v = ror_add<0x121>(v);   // row_ror:1
    v = ror_add<0x122>(v);   // row_ror:2
    v = ror_add<0x124>(v);   // row_ror:4
    v = ror_add<0x128>(v);   // row_ror:8
    return v;                // every lane: sum over its 16-lane row
}

__global__ __launch_bounds__(256)
__attribute__((amdgpu_waves_per_eu(4, 4)))
void phm_fused(const float* __restrict__ x,
               const float* __restrict__ rule_d,
               const float* __restrict__ Wl_d,
               const float* __restrict__ Wr_d,
               const float* __restrict__ bias_d,
               const float* __restrict__ rule_u,
               const float* __restrict__ Wl_u,
               const float* __restrict__ Wr_u,
               const float* __restrict__ bias_u,
               float* __restrict__ out,
               int n_tokens)
{
    __shared__ __attribute__((aligned(16))) float sTile[T_TILE * 768]; // 24 KB in/out, in-place
    __shared__ __attribute__((aligned(16))) float sLd[768];   // W_left_d  [i][p]  i*192+p
    __shared__ __attribute__((aligned(16))) float sRu[768];   // W_right_u [i][q2] i*192+q2
    __shared__ __attribute__((aligned(16))) float sBu[768];   // bias_u    [o]

    const int tid = threadIdx.x;
    for (int i = tid; i < 768; i += 256) sLd[i] = Wl_d[i];
    for (int i = tid; i < 768; i += 256) sRu[i] = Wr_u[i];
    for (int i = tid; i < 768; i += 256) sBu[i] = bias_u[i];

    const int lane = tid & 63;
    const int wave = tid >> 6;
    const int a    = lane >> 4;   // kron block 0..3 (also c for z-phase outputs)
    const int r    = lane & 15;   // slot within block

    // ---- SMALL per-lane-constant weights -> registers (59 floats) ----
    float rD[4][4], rU[4][4];      // [xor_k][i] = rule[i][a^k][a]
    #pragma unroll
    for (int k = 0; k < 4; ++k)
        #pragma unroll
        for (int i = 0; i < 4; ++i) {
            rD[k][i] = rule_d[i*16 + (a^k)*4 + a];
            rU[k][i] = rule_u[i*16 + (a^k)*4 + a];
        }
    float lu[4][3];                // W_left_u[i][3r+w]
    #pragma unroll
    for (int i = 0; i < 4; ++i)
        #pragma unroll
        for (int w = 0; w < 3; ++w) lu[i][w] = Wl_u[i*48 + 3*r + w];
    float bd[3];                   // bias_d at o = a*48 + 3r + w
    float rdw[4][3];               // W_right_d[i][3r+w]
    #pragma unroll
    for (int w = 0; w < 3; ++w) bd[w] = bias_d[a*48 + 3*r + w];
    #pragma unroll
    for (int i = 0; i < 4; ++i)
        #pragma unroll
        for (int w = 0; w < 3; ++w) rdw[i][w] = Wr_d[i*48 + 3*r + w];

    const long long total4 = (long long)n_tokens * 192;   // total float4 count
    const int n_tiles = (n_tokens + T_TILE - 1) / T_TILE;

    // ---- prologue: prefetch first tile into registers ----
    float4 pf[6];
    {
        const long long g4 = (long long)blockIdx.x * (T_TILE * 192);
        #pragma unroll
        for (int j = 0; j < 6; ++j) {
            const long long gi = g4 + tid + j * 256;
            pf[j] = make_float4(0.f, 0.f, 0.f, 0.f);
            if (gi < total4) pf[j] = *(const float4*)(x + gi * 4);
        }
    }
    __syncthreads();   // weights staged

    for (int tile = blockIdx.x; tile < n_tiles; tile += gridDim.x) {
        // ---- commit prefetched tile to LDS ----
        #pragma unroll
        for (int j = 0; j < 6; ++j)
            *(float4*)&sTile[(tid + j * 256) * 4] = pf[j];
        __syncthreads();

        // ---- issue NEXT tile's loads now; results used next iteration ----
        {
            const long long g4n = (long long)(tile + gridDim.x) * (T_TILE * 192);
            #pragma unroll
            for (int j = 0; j < 6; ++j) {
                const long long gi = g4n + tid + j * 256;
                pf[j] = make_float4(0.f, 0.f, 0.f, 0.f);
                if (gi < total4) pf[j] = *(const float4*)(x + gi * 4);
            }
        }

        // ---- compute: wave's TWO tokens in one pass (weight reads shared) ----
        float* xt0 = &sTile[(wave*2) * 768 + a*192 + 12*r];
        float* xt1 = xt0 + 768;
        float4 xv0[3], xv1[3];
        #pragma unroll
        for (int u = 0; u < 3; ++u) {
            xv0[u] = *(const float4*)(xt0 + 4*u);
            xv1[u] = *(const float4*)(xt1 + 4*u);
        }

        // down dots (one sLd read feeds both tokens), DPP 16-lane reduce
        float sd0[4], sd1[4];
        #pragma unroll
        for (int i = 0; i < 4; ++i) {
            float a0 = 0.f, a1 = 0.f;
            #pragma unroll
            for (int u = 0; u < 3; ++u) {
                const float4 lv = *(const float4*)(&sLd[i*192 + 12*r + 4*u]);
                a0 = fmaf(xv0[u].x, lv.x, a0);  a1 = fmaf(xv1[u].x, lv.x, a1);
                a0 = fmaf(xv0[u].y, lv.y, a0);  a1 = fmaf(xv1[u].y, lv.y, a1);
                a0 = fmaf(xv0[u].z, lv.z, a0);  a1 = fmaf(xv1[u].z, lv.z, a1);
                a0 = fmaf(xv0[u].w, lv.w, a0);  a1 = fmaf(xv1[u].w, lv.w, a1);
            }
            sd0[i] = reduce16(a0);
            sd1[i] = reduce16(a1);
        }

        // cross-group gather: 3 xor-shuffles per (i, token)
        float tD0[4], tD1[4];
        #pragma unroll
        for (int i = 0; i < 4; ++i) {
            float x1 = __shfl_xor(sd0[i], 16);
            float x2 = __shfl_xor(sd0[i], 32);
            float x3 = __shfl_xor(x1,     32);
            tD0[i] = fmaf(sd0[i], rD[0][i], fmaf(x1, rD[1][i],
                     fmaf(x2,     rD[2][i],      x3 * rD[3][i])));
            x1 = __shfl_xor(sd1[i], 16);
            x2 = __shfl_xor(sd1[i], 32);
            x3 = __shfl_xor(x1,     32);
            tD1[i] = fmaf(sd1[i], rD[0][i], fmaf(x1, rD[1][i],
                     fmaf(x2,     rD[2][i],      x3 * rD[3][i])));
        }

        // z + gelu at o = a*48 + 3r + w, both tokens
        float g0[3], g1[3];
        #pragma unroll
        for (int w = 0; w < 3; ++w) {
            float z0 = bd[w], z1 = bd[w];
            #pragma unroll
            for (int i = 0; i < 4; ++i) {
                z0 = fmaf(tD0[i], rdw[i][w], z0);
                z1 = fmaf(tD1[i], rdw[i][w], z1);
            }
            const float i0 = SQ2PI * fmaf(0.044715f*z0, z0*z0, z0);
            const float i1 = SQ2PI * fmaf(0.044715f*z1, z1*z1, z1);
            const float e0 = __expf(2.0f*i0);              // tanh(y)=1-2/(e^{2y}+1)
            const float e1 = __expf(2.0f*i1);
            g0[w] = 0.5f*z0*(1.0f + (1.0f - 2.0f/(e0 + 1.0f)));
            g1[w] = 0.5f*z1*(1.0f + (1.0f - 2.0f/(e1 + 1.0f)));
        }

        // up dots + DPP reduce + gather + rule contraction
        float tU0[4], tU1[4];
        #pragma unroll
        for (int i = 0; i < 4; ++i) {
            float a0 = 0.f, a1 = 0.f;
            #pragma unroll
            for (int w = 0; w < 3; ++w) {
                a0 = fmaf(g0[w], lu[i][w], a0);
                a1 = fmaf(g1[w], lu[i][w], a1);
            }
            const float h0 = reduce16(a0);
            const float h1 = reduce16(a1);
            float x1 = __shfl_xor(h0, 16);
            float x2 = __shfl_xor(h0, 32);
            float x3 = __shfl_xor(x1, 32);
            tU0[i] = fmaf(h0, rU[0][i], fmaf(x1, rU[1][i],
                     fmaf(x2, rU[2][i],      x3 * rU[3][i])));
            x1 = __shfl_xor(h1, 16);
            x2 = __shfl_xor(h1, 32);
            x3 = __shfl_xor(x1, 32);
            tU1[i] = fmaf(h1, rU[0][i], fmaf(x1, rU[1][i],
                     fmaf(x2, rU[2][i],      x3 * rU[3][i])));
        }

        // outputs back IN PLACE (lane overwrites exactly what it read; one
        // sRu/sBu read per u feeds both tokens)
        #pragma unroll
        for (int u = 0; u < 3; ++u) {
            const float4 b = *(const float4*)(&sBu[a*192 + 12*r + 4*u]);
            float4 ov0 = b, ov1 = b;
            #pragma unroll
            for (int i = 0; i < 4; ++i) {
                const float4 ru = *(const float4*)(&sRu[i*192 + 12*r + 4*u]);
                ov0.x = fmaf(tU0[i], ru.x, ov0.x);  ov1.x = fmaf(tU1[i], ru.x, ov1.x);
                ov0.y = fmaf(tU0[i], ru.y, ov0.y);  ov1.y = fmaf(tU1[i], ru.y, ov1.y);
                ov0.z = fmaf(tU0[i], ru.z, ov0.z);  ov1.z = fmaf(tU1[i], ru.z, ov1.z);
                ov0.w = fmaf(tU0[i], ru.w, ov0.w);  ov1.w = fmaf(tU1[i], ru.w, ov1.w);
            }
            *(float4*)(xt0 + 4*u) = ov0;
            *(float4*)(xt1 + 4*u) = ov1;
        }
        __syncthreads();

        // ---- cooperative coalesced store ----
        const long long g4 = (long long)tile * (T_TILE * 192);
        #pragma unroll
        for (int j = 0; j < 6; ++j) {
            const int idx = tid + j * 256;
            const long long gi = g4 + idx;
            if (gi < total4)
                *(float4*)(out + gi * 4) = *(const float4*)&sTile[idx * 4];
        }
        __syncthreads();   // store done before next iter overwrites sTile
    }
}

extern "C" void kernel_launch(void* const* d_in, const int* in_sizes, int n_in,
                              void* d_out, int out_size, void* d_ws, size_t ws_size,
                              hipStream_t stream) {
    const float* x      = (const float*)d_in[0];
    const float* rule_d = (const float*)d_in[1];
    const float* Wl_d   = (const float*)d_in[2];
    const float* Wr_d   = (const float*)d_in[3];
    const float* bias_d = (const float*)d_in[4];
    const float* rule_u = (const float*)d_in[5];
    const float* Wl_u   = (const float*)d_in[6];
    const float* Wr_u   = (const float*)d_in[7];
    const float* bias_u = (const float*)d_in[8];
    float* out          = (float*)d_out;

    const int n_tokens = in_sizes[0] / 768;   // 32768

    phm_fused<<<dim3(1024), dim3(256), 0, stream>>>(
        x, rule_d, Wl_d, Wr_d, bias_d, rule_u, Wl_u, Wr_u, bias_u, out, n_tokens);
}

// Round 6
// 192.184 us; speedup vs baseline: 1.1150x; 1.1150x over previous
//
#include <hip/hip_runtime.h>
#include <math.h>

// PHM adapter: down (768->192, n=4 rank-1 kron) -> gelu_new -> up (192->768).
// Round 6: BARRIER-FREE. Rounds 2-5 were latency-bound (75-85us vs ~23us
// floor, all pipes <40%): block-wide load->barrier->compute->barrier->store
// exposes global latency per tile, and register prefetch spills (compiler
// pins VGPR target at 64: rounds 3/4/5 all spilled; round 5's pf[6] went to
// scratch wholesale, +24576KB WRITE). New structure: each WAVE independently
// processes a contiguous token pair through its PRIVATE 6KB LDS scratch --
// intra-wave LDS hazards only (lgkmcnt-ordered), NO __syncthreads in the
// loop. Latency hidden by 16+ independent waves/CU. Register use kept under
// the 64-VGPR cap by design (27 persistent + <30 transient).

#define SQ2PI 0.79788456080286535588f

template<int CTRL>
__device__ __forceinline__ float ror_add(float v) {
    // v + rotate_within_16(v, CTRL)  (DPP row_ror — VALU pipe, no DS traffic)
    int s = __builtin_amdgcn_update_dpp(0, __float_as_int(v), CTRL, 0xF, 0xF, true);
    return v + __int_as_float(s);
}
__device__ __forceinline__ float reduce16(float v) {
    v = ror_add<0x121>(v);   // row_ror:1
    v = ror_add<0x122>(v);   // row_ror:2
    v = ror_add<0x124>(v);   // row_ror:4
    v = ror_add<0x128>(v);   // row_ror:8
    return v;                // every lane: sum over its 16-lane row
}

__global__ __launch_bounds__(256)
void phm_fused(const float* __restrict__ x,
               const float* __restrict__ rule_d,
               const float* __restrict__ Wl_d,
               const float* __restrict__ Wr_d,
               const float* __restrict__ bias_d,
               const float* __restrict__ rule_u,
               const float* __restrict__ Wl_u,
               const float* __restrict__ Wr_u,
               const float* __restrict__ bias_u,
               float* __restrict__ out,
               int n_tokens)
{
    __shared__ __attribute__((aligned(16))) float sW[4][1536]; // per-wave 2-token scratch (24 KB)
    __shared__ __attribute__((aligned(16))) float sLd[768];    // W_left_d  [i][p]  i*192+p
    __shared__ __attribute__((aligned(16))) float sRu[768];    // W_right_u [i][q2] i*192+q2
    __shared__ __attribute__((aligned(16))) float sLu[192];    // W_left_u  [i][q]  i*48+q
    __shared__ float sRuleD[64];                               // [i][a'][c] i*16+a'*4+c
    __shared__ float sRuleU[64];

    const int tid = threadIdx.x;
    for (int i = tid; i < 768; i += 256) sLd[i] = Wl_d[i];
    for (int i = tid; i < 768; i += 256) sRu[i] = Wr_u[i];
    if (tid < 192)      sLu[tid]        = Wl_u[tid];
    if (tid < 64)       sRuleD[tid]     = rule_d[tid];
    else if (tid < 128) sRuleU[tid-64]  = rule_u[tid-64];

    const int lane = tid & 63;
    const int wave = tid >> 6;
    const int a    = lane >> 4;   // kron block 0..3 (also dest c for this lane)
    const int r    = lane & 15;   // slot within block

    // ---- SMALL persistent registers only (27 floats) ----
    float bd[3];                   // bias_d at o = a*48 + 3r + w
    float rdw[4][3];               // W_right_d[i][3r+w]
    float4 bu[3];                  // bias_u at o = a*192 + 12r + 4u
    #pragma unroll
    for (int w = 0; w < 3; ++w) bd[w] = bias_d[a*48 + 3*r + w];
    #pragma unroll
    for (int i = 0; i < 4; ++i)
        #pragma unroll
        for (int w = 0; w < 3; ++w) rdw[i][w] = Wr_d[i*48 + 3*r + w];
    #pragma unroll
    for (int u = 0; u < 3; ++u)
        bu[u] = *(const float4*)(bias_u + a*192 + 12*r + 4*u);

    __syncthreads();   // the ONLY block barrier: weights staged

    float* W = sW[wave];
    const int wid     = blockIdx.x * 4 + wave;
    const int n_waves = gridDim.x * 4;
    const int n_pairs = n_tokens >> 1;          // token pairs (contiguous 6 KB)

    for (int pr = wid; pr < n_pairs; pr += n_waves) {
        const float* xp = x + (size_t)pr * 1536;

        // ---- coalesced load (6 x 1KB contiguous per wave) -> wave scratch ----
        #pragma unroll
        for (int j = 0; j < 6; ++j) {
            const float4 v = *(const float4*)(xp + (lane + 64*j) * 4);
            *(float4*)&W[(lane + 64*j) * 4] = v;
        }
        // (compiler inserts lgkmcnt waits; all hazards intra-wave)

        // ---- down dots, per-u to limit register liveness ----
        float s0[4] = {0,0,0,0}, s1[4] = {0,0,0,0};
        #pragma unroll
        for (int u = 0; u < 3; ++u) {
            const float4 xa = *(const float4*)&W[      a*192 + 12*r + 4*u];
            const float4 xb = *(const float4*)&W[768 + a*192 + 12*r + 4*u];
            #pragma unroll
            for (int i = 0; i < 4; ++i) {
                const float4 lv = *(const float4*)&sLd[i*192 + 12*r + 4*u];
                s0[i] = fmaf(xa.x, lv.x, s0[i]);  s1[i] = fmaf(xb.x, lv.x, s1[i]);
                s0[i] = fmaf(xa.y, lv.y, s0[i]);  s1[i] = fmaf(xb.y, lv.y, s1[i]);
                s0[i] = fmaf(xa.z, lv.z, s0[i]);  s1[i] = fmaf(xb.z, lv.z, s1[i]);
                s0[i] = fmaf(xa.w, lv.w, s0[i]);  s1[i] = fmaf(xb.w, lv.w, s1[i]);
            }
        }

        // ---- 16-lane DPP reduce + xor-swizzle gather + rule contraction ----
        float tD0[4], tD1[4];
        #pragma unroll
        for (int i = 0; i < 4; ++i) {
            const float rk0 = sRuleD[i*16 + (a^0)*4 + a];   // broadcast reads
            const float rk1 = sRuleD[i*16 + (a^1)*4 + a];
            const float rk2 = sRuleD[i*16 + (a^2)*4 + a];
            const float rk3 = sRuleD[i*16 + (a^3)*4 + a];
            const float h0 = reduce16(s0[i]);
            const float h1 = reduce16(s1[i]);
            float x1 = __shfl_xor(h0, 16), x2 = __shfl_xor(h0, 32), x3 = __shfl_xor(x1, 32);
            tD0[i] = fmaf(h0, rk0, fmaf(x1, rk1, fmaf(x2, rk2, x3 * rk3)));
            x1 = __shfl_xor(h1, 16); x2 = __shfl_xor(h1, 32); x3 = __shfl_xor(x1, 32);
            tD1[i] = fmaf(h1, rk0, fmaf(x1, rk1, fmaf(x2, rk2, x3 * rk3)));
        }

        // ---- z + gelu at o = a*48 + 3r + w ----
        float g0[3], g1[3];
        #pragma unroll
        for (int w = 0; w < 3; ++w) {
            float z0 = bd[w], z1 = bd[w];
            #pragma unroll
            for (int i = 0; i < 4; ++i) {
                z0 = fmaf(tD0[i], rdw[i][w], z0);
                z1 = fmaf(tD1[i], rdw[i][w], z1);
            }
            const float i0 = SQ2PI * fmaf(0.044715f*z0, z0*z0, z0);
            const float i1 = SQ2PI * fmaf(0.044715f*z1, z1*z1, z1);
            const float e0 = __expf(2.0f*i0);                // tanh(y)=1-2/(e^{2y}+1)
            const float e1 = __expf(2.0f*i1);
            g0[w] = 0.5f*z0*(1.0f + (1.0f - 2.0f/(e0 + 1.0f)));
            g1[w] = 0.5f*z1*(1.0f + (1.0f - 2.0f/(e1 + 1.0f)));
        }

        // ---- up dots + reduce + gather + rule contraction ----
        float tU0[4], tU1[4];
        #pragma unroll
        for (int i = 0; i < 4; ++i) {
            const float l0 = sLu[i*48 + 3*r + 0];
            const float l1 = sLu[i*48 + 3*r + 1];
            const float l2 = sLu[i*48 + 3*r + 2];
            const float rk0 = sRuleU[i*16 + (a^0)*4 + a];
            const float rk1 = sRuleU[i*16 + (a^1)*4 + a];
            const float rk2 = sRuleU[i*16 + (a^2)*4 + a];
            const float rk3 = sRuleU[i*16 + (a^3)*4 + a];
            float a0 = g0[0]*l0 + g0[1]*l1 + g0[2]*l2;
            float a1 = g1[0]*l0 + g1[1]*l1 + g1[2]*l2;
            const float h0 = reduce16(a0);
            const float h1 = reduce16(a1);
            float x1 = __shfl_xor(h0, 16), x2 = __shfl_xor(h0, 32), x3 = __shfl_xor(x1, 32);
            tU0[i] = fmaf(h0, rk0, fmaf(x1, rk1, fmaf(x2, rk2, x3 * rk3)));
            x1 = __shfl_xor(h1, 16); x2 = __shfl_xor(h1, 32); x3 = __shfl_xor(x1, 32);
            tU1[i] = fmaf(h1, rk0, fmaf(x1, rk1, fmaf(x2, rk2, x3 * rk3)));
        }

        // ---- outputs IN PLACE in scratch (lane overwrites what it read) ----
        #pragma unroll
        for (int u = 0; u < 3; ++u) {
            float4 ov0 = bu[u], ov1 = bu[u];
            #pragma unroll
            for (int i = 0; i < 4; ++i) {
                const float4 ru = *(const float4*)&sRu[i*192 + 12*r + 4*u];
                ov0.x = fmaf(tU0[i], ru.x, ov0.x);  ov1.x = fmaf(tU1[i], ru.x, ov1.x);
                ov0.y = fmaf(tU0[i], ru.y, ov0.y);  ov1.y = fmaf(tU1[i], ru.y, ov1.y);
                ov0.z = fmaf(tU0[i], ru.z, ov0.z);  ov1.z = fmaf(tU1[i], ru.z, ov1.z);
                ov0.w = fmaf(tU0[i], ru.w, ov0.w);  ov1.w = fmaf(tU1[i], ru.w, ov1.w);
            }
            *(float4*)&W[      a*192 + 12*r + 4*u] = ov0;
            *(float4*)&W[768 + a*192 + 12*r + 4*u] = ov1;
        }

        // ---- coalesced store from scratch ----
        float* op = out + (size_t)pr * 1536;
        #pragma unroll
        for (int j = 0; j < 6; ++j) {
            const float4 v = *(const float4*)&W[(lane + 64*j) * 4];
            *(float4*)(op + (lane + 64*j) * 4) = v;
        }
    }
}

extern "C" void kernel_launch(void* const* d_in, const int* in_sizes, int n_in,
                              void* d_out, int out_size, void* d_ws, size_t ws_size,
                              hipStream_t stream) {
    const float* x      = (const float*)d_in[0];
    const float* rule_d = (const float*)d_in[1];
    const float* Wl_d   = (const float*)d_in[2];
    const float* Wr_d   = (const float*)d_in[3];
    const float* bias_d = (const float*)d_in[4];
    const float* rule_u = (const float*)d_in[5];
    const float* Wl_u   = (const float*)d_in[6];
    const float* Wr_u   = (const float*)d_in[7];
    const float* bias_u = (const float*)d_in[8];
    float* out          = (float*)d_out;

    const int n_tokens = in_sizes[0] / 768;   // 32768

    // 1024 blocks = 4096 waves; 16384 pairs -> exactly 4 pairs/wave, balanced.
    phm_fused<<<dim3(1024), dim3(256), 0, stream>>>(
        x, rule_d, Wl_d, Wr_d, bias_d, rule_u, Wl_u, Wr_u, bias_u, out, n_tokens);
}